// Round 8
// baseline (44.002 us; speedup 1.0000x reference)
//
#include <hip/hip_runtime.h>

#define D 64
#define K 1024
#define NVEC 65536
#define MB 128            // vectors per block
#define NBLK (NVEC / MB)  // 512
#define WAVES 4
#define KPW (K / WAVES)   // 256 codes per wave
#define TILES (KPW / 16)  // 16
#define NG (MB / 16)      // 8 vector groups per wave

typedef __attribute__((ext_vector_type(8))) short bf16x8;
typedef __attribute__((ext_vector_type(4))) float f32x4;
typedef __attribute__((ext_vector_type(4))) int i32x4;

// single v_perm_b32: {hi16(b), hi16(a)} == bf16x2(trunc(a), trunc(b))
__device__ inline unsigned pk2t(float a, float b) {
    return __builtin_amdgcn_perm(__builtin_bit_cast(unsigned, b),
                                 __builtin_bit_cast(unsigned, a), 0x07060302u);
}

// ---------------------------------------------------------------------------
// Fused main kernel: stage z -> on-the-fly bf16 codebook (v_perm) -> MFMA
// score GEMM -> packed argmax -> gather/write + EXACT f32 loss partial.
// Loss partials go to ws; a second kernel reduces them (kernel boundary =
// guaranteed coherence; single-kernel cross-XCD finisher failed twice).
// ---------------------------------------------------------------------------
__global__ __launch_bounds__(256, 2) void vq_fused(const float* __restrict__ z,
                                                   const float* __restrict__ emb,
                                                   float* __restrict__ out,
                                                   float* __restrict__ pP) {
    __shared__ __align__(16) char zl[MB * 128];   // 16 KB bf16 z-tile [v][d], XOR-swizzled
    __shared__ __align__(16) float hbl[K];        // 4 KB: 1 - 0.5||e||^2
    __shared__ int   wv[WAVES * MB];
    __shared__ int   fin[MB];
    __shared__ float red[256];

    const int tid = threadIdx.x;
    const int blk = blockIdx.x;
    const int b   = blk >> 3;              // batch (8 blocks per batch)
    const int hw0 = (blk & 7) * MB;        // first spatial pos
    const float* zb = z + (size_t)b * (D * 1024) + hw0;

    const int wave = tid >> 6;
    const int lane = tid & 63;
    const int cw   = wave * KPW;

    // ---- Phase A: stage z tile f32 [d][v] -> LDS bf16 [v][d] swizzled
#pragma unroll
    for (int it = 0; it < 2; ++it) {
        const int item = it * 256 + tid;   // 0..511
        const int v4 = item & 31;          // 4-vector group (128 v)
        const int d4 = item >> 5;          // 4-dim group (64 d)
        float4 r[4];
#pragma unroll
        for (int i = 0; i < 4; ++i)
            r[i] = *reinterpret_cast<const float4*>(zb + (size_t)(d4 * 4 + i) * 1024 + v4 * 4);
        const float* rf = reinterpret_cast<const float*>(r);
#pragma unroll
        for (int j = 0; j < 4; ++j) {
            const int v = v4 * 4 + j;
            uint2 pk;
            pk.x = pk2t(rf[0 * 4 + j], rf[1 * 4 + j]);
            pk.y = pk2t(rf[2 * 4 + j], rf[3 * 4 + j]);
            const int byte = v * 128 + ((d4 * 8) ^ ((v & 7) << 4));
            *reinterpret_cast<uint2*>(zl + byte) = pk;
        }
    }

    // ---- Phase B: this wave's 256 biased neg half-norms -> LDS (exact f32)
#pragma unroll
    for (int j = 0; j < 4; ++j) {
        const int row = cw + lane + 64 * j;
        const float4* rp = reinterpret_cast<const float4*>(emb + (size_t)row * D);
        float s = 0.f;
#pragma unroll
        for (int i = 0; i < 16; ++i) {
            const float4 v = rp[i];
            s = fmaf(v.x, v.x, s); s = fmaf(v.y, v.y, s);
            s = fmaf(v.z, v.z, s); s = fmaf(v.w, v.w, s);
        }
        hbl[row] = 1.0f - 0.5f * s;
    }
    __syncthreads();

    const int l16 = lane & 15;
    const int lg  = lane >> 4;    // 0..3

    // ---- B-frags: this block's 128 vectors in registers
    bf16x8 bfr[NG][2];
#pragma unroll
    for (int g = 0; g < NG; ++g)
#pragma unroll
        for (int h = 0; h < 2; ++h) {
            const int v = g * 16 + l16;
            const int byte = v * 128 + (((h * 64) + lg * 16) ^ ((v & 7) << 4));
            bfr[g][h] = *reinterpret_cast<const bf16x8*>(zl + byte);
        }

    // ---- k-loop: 16 codes/tile; v_perm f32->bf16 A-frags; packed argmax
    int best[NG];
#pragma unroll
    for (int g = 0; g < NG; ++g) best[g] = 0;
#pragma unroll 2
    for (int kt = 0; kt < TILES; ++kt) {
        const int cbase = cw + kt * 16;
        const float4* rp = reinterpret_cast<const float4*>(emb + (size_t)(cbase + l16) * D);
        const float4 f0 = rp[lg * 2];
        const float4 f1 = rp[lg * 2 + 1];
        const float4 f2 = rp[8 + lg * 2];
        const float4 f3 = rp[8 + lg * 2 + 1];
        i32x4 ai0 = { (int)pk2t(f0.x, f0.y), (int)pk2t(f0.z, f0.w),
                      (int)pk2t(f1.x, f1.y), (int)pk2t(f1.z, f1.w) };
        i32x4 ai1 = { (int)pk2t(f2.x, f2.y), (int)pk2t(f2.z, f2.w),
                      (int)pk2t(f3.x, f3.y), (int)pk2t(f3.z, f3.w) };
        const bf16x8 a0 = __builtin_bit_cast(bf16x8, ai0);
        const bf16x8 a1 = __builtin_bit_cast(bf16x8, ai1);
        const f32x4 ci = *reinterpret_cast<const f32x4*>(&hbl[cbase + lg * 4]);
        const int idx0 = cbase + lg * 4;
#pragma unroll
        for (int g = 0; g < NG; ++g) {
            f32x4 c = ci;
            c = __builtin_amdgcn_mfma_f32_16x16x32_bf16(a0, bfr[g][0], c, 0, 0, 0);
            c = __builtin_amdgcn_mfma_f32_16x16x32_bf16(a1, bfr[g][1], c, 0, 0, 0);
#pragma unroll
            for (int r = 0; r < 4; ++r) {
                const int pk = (int)((__builtin_bit_cast(unsigned, c[r]) & 0xFFFFFC00u)
                                     | (unsigned)(idx0 + r));
                best[g] = best[g] > pk ? best[g] : pk;
            }
        }
    }

    // ---- cross-lane argmax (over lg groups)
#pragma unroll
    for (int g = 0; g < NG; ++g) {
        int tv = best[g];
        int o = __shfl_xor(tv, 16, 64); tv = tv > o ? tv : o;
        o = __shfl_xor(tv, 32, 64);     tv = tv > o ? tv : o;
        if (lane < 16) wv[wave * MB + g * 16 + l16] = tv;
    }
    __syncthreads();

    // ---- cross-wave combine -> final index per vector (selection only)
    if (tid < MB) {
        int tv = wv[tid];
#pragma unroll
        for (int w = 1; w < WAVES; ++w) {
            const int o = wv[w * MB + tid];
            tv = tv > o ? tv : o;
        }
        fin[tid] = tv & (K - 1);
    }
    __syncthreads();

    // ---- output + EXACT loss: gather exact f32 code row, re-read exact z,
    //      write out[b][d][hw], accumulate (q - z)^2 in f32.
    float sse = 0.f;
    {
        const int v  = tid & 127;
        const int dh = tid >> 7;              // 0..1, 32 dims each
        const int idx = fin[v];
        const float4* eq4 = reinterpret_cast<const float4*>(emb + (size_t)idx * D + dh * 32);
        const float* zc = zb + v;             // + d*1024
        float* ob = out + (size_t)b * (D * 1024) + hw0 + v;
#pragma unroll
        for (int i = 0; i < 8; ++i) {
            const float4 q = eq4[i];
            const int d = dh * 32 + i * 4;
            const float z0 = zc[(size_t)(d + 0) * 1024];
            const float z1 = zc[(size_t)(d + 1) * 1024];
            const float z2 = zc[(size_t)(d + 2) * 1024];
            const float z3 = zc[(size_t)(d + 3) * 1024];
            ob[(size_t)(d + 0) * 1024] = q.x;
            ob[(size_t)(d + 1) * 1024] = q.y;
            ob[(size_t)(d + 2) * 1024] = q.z;
            ob[(size_t)(d + 3) * 1024] = q.w;
            const float e0 = q.x - z0; sse = fmaf(e0, e0, sse);
            const float e1 = q.y - z1; sse = fmaf(e1, e1, sse);
            const float e2 = q.z - z2; sse = fmaf(e2, e2, sse);
            const float e3 = q.w - z3; sse = fmaf(e3, e3, sse);
        }
    }

    // ---- block partial: fixed-order tree, plain store (coherent at kernel end)
    red[tid] = sse;
    __syncthreads();
#pragma unroll
    for (int s = 128; s > 0; s >>= 1) {
        if (tid < s) red[tid] += red[tid + s];
        __syncthreads();
    }
    if (tid == 0) pP[blk] = red[0];
}

// ---------------------------------------------------------------------------
// Loss epilogue: 1 block; kernel boundary guarantees pP visibility.
// ---------------------------------------------------------------------------
__global__ __launch_bounds__(256) void vq_loss(const float* __restrict__ pP,
                                               float* __restrict__ loss_out) {
    __shared__ float red[256];
    float s = 0.f;
    for (int i = threadIdx.x; i < NBLK; i += 256) s += pP[i];
    red[threadIdx.x] = s;
    __syncthreads();
#pragma unroll
    for (int st = 128; st > 0; st >>= 1) {
        if (threadIdx.x < st) red[threadIdx.x] += red[threadIdx.x + st];
        __syncthreads();
    }
    if (threadIdx.x == 0)
        loss_out[0] = 1.25f * red[0] * (1.0f / (float)((size_t)NVEC * D));
}

extern "C" void kernel_launch(void* const* d_in, const int* in_sizes, int n_in,
                              void* d_out, int out_size, void* d_ws, size_t ws_size,
                              hipStream_t stream) {
    const float* z   = (const float*)d_in[0];   // [64, 64, 32, 32]
    const float* emb = (const float*)d_in[1];   // [1024, 64]
    float* out = (float*)d_out;                 // 4194304 quantized + 1 loss

    float* pP = (float*)d_ws;                   // 512 block partials

    vq_fused<<<NBLK, 256, 0, stream>>>(z, emb, out, pP);
    vq_loss<<<1, 256, 0, stream>>>(pP, out + (size_t)NVEC * D);
}